// Round 1
// baseline (381.192 us; speedup 1.0000x reference)
//
#include <hip/hip_runtime.h>
#include <hip/hip_fp16.h>
#include <stdint.h>

#define TS 200

typedef _Float16 h2_t  __attribute__((ext_vector_type(2)));
typedef _Float16 f16x8 __attribute__((ext_vector_type(8)));
typedef float    f32x4 __attribute__((ext_vector_type(4)));

static __device__ __forceinline__ float fdot2f(uint32_t w, uint32_t h, float acc) {
#if __has_builtin(__builtin_amdgcn_fdot2)
    return __builtin_amdgcn_fdot2(__builtin_bit_cast(h2_t, w),
                                  __builtin_bit_cast(h2_t, h), acc, false);
#else
    h2_t a = __builtin_bit_cast(h2_t, w), b = __builtin_bit_cast(h2_t, h);
    acc = fmaf((float)a.x, (float)b.x, acc);
    acc = fmaf((float)a.y, (float)b.y, acc);
    return acc;
#endif
}

template <int CTRL>
static __device__ __forceinline__ float dpp_add(float x) {
    int m = __builtin_amdgcn_update_dpp(0, __builtin_bit_cast(int, x), CTRL, 0xF, 0xF, true);
    return x + __builtin_bit_cast(float, m);
}
template <int CTRL>
static __device__ __forceinline__ float dpp_mov(float x) {
    int m = __builtin_amdgcn_update_dpp(0, __builtin_bit_cast(int, x), CTRL, 0xF, 0xF, true);
    return __builtin_bit_cast(float, m);
}

// ---------------------------------------------------------------------------
// K0: one-time packs (unchanged).
//  blocks [0,6400):     xh[row=b*200+t][k] = f16(x[b][10t][k])
//  blocks [6400,8448):  wxt[n=c*512+g*256+u][k] = f16(Wx[c][g][k][u])
//  blocks [8448,9472):  wp: W_h fp16 pairs, recurrence thread layout
//                       [c][j=16][thr=1024][e=4]; j=a*4+i, a=uu*2+g;
//                       u=(wv*8+uq)*2+uu, v=vs*32+i*8+e*2, thr=wv*64+uq*8+vs.
// ---------------------------------------------------------------------------
__global__ __launch_bounds__(256) void pack_all(const float* __restrict__ x,
                                                const float* __restrict__ Wx,
                                                const float* __restrict__ Wh,
                                                _Float16* __restrict__ xh,
                                                _Float16* __restrict__ wxt,
                                                uint32_t* __restrict__ wp) {
    int bid = blockIdx.x, tid = threadIdx.x;
    if (bid < 6400) {
        int row = bid, col = tid;
        int b = row / 200, t = row - b * 200;
        xh[(size_t)row * 256 + col] = (_Float16)x[((size_t)(b * 2000 + t * 10)) * 256 + col];
    } else if (bid < 8448) {
        int n = bid - 6400, k = tid;
        wxt[(size_t)n * 256 + k] = (_Float16)Wx[((size_t)((n >> 8) * 256 + k)) * 256 + (n & 255)];
    } else {
        int idx = (bid - 8448) * 256 + tid;          // [0, 262144)
        int e   = idx & 3;
        int thr = (idx >> 2) & 1023;
        int j   = (idx >> 12) & 15;
        int c   = idx >> 16;
        int a = j >> 2, i = j & 3;
        int uu = a >> 1, g = a & 1;
        int vs = thr & 7, uq = (thr >> 3) & 7, wv = thr >> 6;
        int u = (wv * 8 + uq) * 2 + uu;
        int v = vs * 32 + i * 8 + e * 2;
        const float* base = Wh + ((size_t)((c * 2 + g) * 256 + v)) * 256 + u;
        h2_t p; p.x = (_Float16)base[0]; p.y = (_Float16)base[256];
        wp[idx] = __builtin_bit_cast(uint32_t, p);
    }
}

// ---------------------------------------------------------------------------
// K1: xp = X[6400x256] * W[256x2048] + bias, f16 MFMA 16x16x32. (unchanged)
// ---------------------------------------------------------------------------
__global__ __launch_bounds__(256) void xp_gemm(const _Float16* __restrict__ xh,
                                               const _Float16* __restrict__ wxt,
                                               const float* __restrict__ bxf,
                                               _Float16* __restrict__ xp) {
    __shared__ _Float16 As[128 * 64];
    __shared__ _Float16 Bs[128 * 64];
    const int tid = threadIdx.x;
    const int lane = tid & 63, w = tid >> 6;
    const int m0 = (blockIdx.x >> 4) * 128;
    const int n0 = (blockIdx.x & 15) * 128;
    const int mw = (w & 1) * 64, nw = (w >> 1) * 64;

    f32x4 acc[4][4] = {};

    for (int kb = 0; kb < 4; kb++) {
        const int k0 = kb * 64;
#pragma unroll
        for (int q = 0; q < 4; q++) {
            int ii = w * 4 + q;
            int r = ii * 8 + (lane >> 3);
            int kcol = (lane & 7) * 8;
            const _Float16* ga = xh  + (size_t)(m0 + r) * 256 + k0 + kcol;
            const _Float16* gb = wxt + (size_t)(n0 + r) * 256 + k0 + kcol;
            __builtin_amdgcn_global_load_lds(
                (const __attribute__((address_space(1))) uint32_t*)ga,
                (__attribute__((address_space(3))) uint32_t*)(As + ii * 512), 16, 0, 0);
            __builtin_amdgcn_global_load_lds(
                (const __attribute__((address_space(1))) uint32_t*)gb,
                (__attribute__((address_space(3))) uint32_t*)(Bs + ii * 512), 16, 0, 0);
        }
        __syncthreads();
#pragma unroll
        for (int kc = 0; kc < 2; kc++) {
            f16x8 a[4], b[4];
#pragma unroll
            for (int mt = 0; mt < 4; mt++)
                a[mt] = *(const f16x8*)&As[(mw + mt * 16 + (lane & 15)) * 64 + kc * 32 + (lane >> 4) * 8];
#pragma unroll
            for (int nt = 0; nt < 4; nt++)
                b[nt] = *(const f16x8*)&Bs[(nw + nt * 16 + (lane & 15)) * 64 + kc * 32 + (lane >> 4) * 8];
#pragma unroll
            for (int mt = 0; mt < 4; mt++)
#pragma unroll
                for (int nt = 0; nt < 4; nt++)
                    acc[mt][nt] = __builtin_amdgcn_mfma_f32_16x16x32_f16(a[mt], b[nt], acc[mt][nt], 0, 0, 0);
        }
        __syncthreads();
    }

    const int nl = lane & 15, quad = lane >> 4;
#pragma unroll
    for (int nt = 0; nt < 4; nt++) {
        int n = n0 + nw + nt * 16 + nl;
        float bias = bxf[n];
        int c = n >> 9, gu = n & 511;
#pragma unroll
        for (int mt = 0; mt < 4; mt++)
#pragma unroll
            for (int r = 0; r < 4; r++) {
                int m = m0 + mw + mt * 16 + quad * 4 + r;
                int b = m / 200, t = m - b * 200;
                xp[((size_t)((c * 32 + b) * 200 + t)) * 512 + gu] =
                    (_Float16)(acc[mt][nt][r] + bias);
            }
    }
}

// ---------------------------------------------------------------------------
// K2: 200-step gated recurrence. 128 WGs (c,b) x 512 threads, 1 WG/CU.
// Each thread owns TWO u-pairs (up0 and up0+64 -> old wp threads tid and
// tid+512 -- wp layout unchanged). 8 independent fdot2 chains per thread
// (ILP), 8 waves/WG (halved barrier group + halved ds_read burst vs the
// 1024-thread version). 32 named pinned uint4 weights (128 VGPR) fit the
// 256-reg budget at waves_per_eu(2,2).
// ---------------------------------------------------------------------------
#define D4(ACC, W, H)                 \
    ACC = fdot2f(W.x, H.x, ACC);      \
    ACC = fdot2f(W.y, H.y, ACC);      \
    ACC = fdot2f(W.z, H.z, ACC);      \
    ACC = fdot2f(W.w, H.w, ACC);

#define PIN4(W) asm volatile("" : "+v"(W.x), "+v"(W.y), "+v"(W.z), "+v"(W.w))

__global__ __attribute__((amdgpu_flat_work_group_size(512, 512),
                          amdgpu_waves_per_eu(2, 2)))
void recurrence(const _Float16* __restrict__ xp,
                const float* __restrict__ bh,
                const uint32_t* __restrict__ Wp,
                float* __restrict__ hs) {
    const int cb  = blockIdx.x;            // c*32+b
    const int c   = cb >> 5;
    const int tid = threadIdx.x;           // 0..511
    const int lane = tid & 63;
    const int vs = lane & 7;
    const int uq = lane >> 3;
    const int wv = tid >> 6;               // 0..7
    const int up0 = wv * 8 + uq;           // 0..63 ; pair B = up0+64
    const int u0 = up0 * 2;                // pair B u = u0+128

    // h2s double buffer: 2 x (8 slices x 20 words) — stride-20 bank partition
    __shared__ __align__(16) uint32_t h2s[2][160];

    // 32 named uint4 weights = 128 half2. Set A = old thread tid, set B = old
    // thread tid+512 (same vs/uq, wv+8 -> upair+64). wp layout unchanged.
    const uint4* wb = (const uint4*)Wp + (size_t)c * 16 * 1024 + tid;
    uint4 wA00 = wb[0 * 1024],        wA01 = wb[1 * 1024],        wA02 = wb[2 * 1024],        wA03 = wb[3 * 1024];
    uint4 wA10 = wb[4 * 1024],        wA11 = wb[5 * 1024],        wA12 = wb[6 * 1024],        wA13 = wb[7 * 1024];
    uint4 wA20 = wb[8 * 1024],        wA21 = wb[9 * 1024],        wA22 = wb[10 * 1024],       wA23 = wb[11 * 1024];
    uint4 wA30 = wb[12 * 1024],       wA31 = wb[13 * 1024],       wA32 = wb[14 * 1024],       wA33 = wb[15 * 1024];
    uint4 wB00 = wb[0 * 1024 + 512],  wB01 = wb[1 * 1024 + 512],  wB02 = wb[2 * 1024 + 512],  wB03 = wb[3 * 1024 + 512];
    uint4 wB10 = wb[4 * 1024 + 512],  wB11 = wb[5 * 1024 + 512],  wB12 = wb[6 * 1024 + 512],  wB13 = wb[7 * 1024 + 512];
    uint4 wB20 = wb[8 * 1024 + 512],  wB21 = wb[9 * 1024 + 512],  wB22 = wb[10 * 1024 + 512], wB23 = wb[11 * 1024 + 512];
    uint4 wB30 = wb[12 * 1024 + 512], wB31 = wb[13 * 1024 + 512], wB32 = wb[14 * 1024 + 512], wB33 = wb[15 * 1024 + 512];
    PIN4(wA00); PIN4(wA01); PIN4(wA02); PIN4(wA03);
    PIN4(wA10); PIN4(wA11); PIN4(wA12); PIN4(wA13);
    PIN4(wA20); PIN4(wA21); PIN4(wA22); PIN4(wA23);
    PIN4(wA30); PIN4(wA31); PIN4(wA32); PIN4(wA33);
    PIN4(wB00); PIN4(wB01); PIN4(wB02); PIN4(wB03);
    PIN4(wB10); PIN4(wB11); PIN4(wB12); PIN4(wB13);
    PIN4(wB20); PIN4(wB21); PIN4(wB22); PIN4(wB23);
    PIN4(wB30); PIN4(wB31); PIN4(wB32); PIN4(wB33);

    // xp / bias for reduce lanes (vs<4): (u = u0 + (vs>>1), g = vs&1); B at +128
    float biasA = 0.f, biasB = 0.f;
    const _Float16* xpb = nullptr;
    if (vs < 4) {
        int g_sel = vs & 1, u_sel = u0 + (vs >> 1);
        biasA = bh[(c * 2 + g_sel) * 256 + u_sel];
        biasB = bh[(c * 2 + g_sel) * 256 + u_sel + 128];
        xpb  = xp + (size_t)cb * 200 * 512 + g_sel * 256 + u_sel;
    }

    float hregA = 0.f, hregB = 0.f;        // valid at vs==0 (u even) / vs==2 (u odd)
    if (tid < 160) { h2s[0][tid] = 0u; }
    __syncthreads();

    float* hsb = hs + (size_t)cb * 200 * 256 + u0;   // B at +128

    for (int t = 0; t < TS; t++) {
        const uint32_t* hbuf = h2s[t & 1];
        uint32_t* hnext = h2s[(t + 1) & 1];

        float xpA = 0.f, xpB = 0.f;
        if (vs < 4) {
            xpA = (float)xpb[(size_t)t * 512];
            xpB = (float)xpb[(size_t)t * 512 + 128];
        }

        uint4 h0 = *(const uint4*)(hbuf + vs * 20 + 0);
        uint4 h1 = *(const uint4*)(hbuf + vs * 20 + 4);
        uint4 h2 = *(const uint4*)(hbuf + vs * 20 + 8);
        uint4 h3 = *(const uint4*)(hbuf + vs * 20 + 12);

        float aA0 = 0.f, aA1 = 0.f, aA2 = 0.f, aA3 = 0.f;
        float aB0 = 0.f, aB1 = 0.f, aB2 = 0.f, aB3 = 0.f;
        // 8 independent chains, A/B interleaved for ILP
        D4(aA0, wA00, h0) D4(aB0, wB00, h0) D4(aA1, wA10, h0) D4(aB1, wB10, h0)
        D4(aA2, wA20, h0) D4(aB2, wB20, h0) D4(aA3, wA30, h0) D4(aB3, wB30, h0)
        D4(aA0, wA01, h1) D4(aB0, wB01, h1) D4(aA1, wA11, h1) D4(aB1, wB11, h1)
        D4(aA2, wA21, h1) D4(aB2, wB21, h1) D4(aA3, wA31, h1) D4(aB3, wB31, h1)
        D4(aA0, wA02, h2) D4(aB0, wB02, h2) D4(aA1, wA12, h2) D4(aB1, wB12, h2)
        D4(aA2, wA22, h2) D4(aB2, wB22, h2) D4(aA3, wA32, h2) D4(aB3, wB32, h2)
        D4(aA0, wA03, h3) D4(aB0, wB03, h3) D4(aA1, wA13, h3) D4(aB1, wB13, h3)
        D4(aA2, wA23, h3) D4(aB2, wB23, h3) D4(aA3, wA33, h3) D4(aB3, wB33, h3)

        aA0 = dpp_add<0x141>(dpp_add<0x4E>(dpp_add<0xB1>(aA0)));
        aA1 = dpp_add<0x141>(dpp_add<0x4E>(dpp_add<0xB1>(aA1)));
        aA2 = dpp_add<0x141>(dpp_add<0x4E>(dpp_add<0xB1>(aA2)));
        aA3 = dpp_add<0x141>(dpp_add<0x4E>(dpp_add<0xB1>(aA3)));
        aB0 = dpp_add<0x141>(dpp_add<0x4E>(dpp_add<0xB1>(aB0)));
        aB1 = dpp_add<0x141>(dpp_add<0x4E>(dpp_add<0xB1>(aB1)));
        aB2 = dpp_add<0x141>(dpp_add<0x4E>(dpp_add<0xB1>(aB2)));
        aB3 = dpp_add<0x141>(dpp_add<0x4E>(dpp_add<0xB1>(aB3)));

        // lane vs -> acc index: vs0:(u even,j) vs1:(u even,k) vs2:(u odd,j) vs3:(u odd,k)
        float sA = (vs == 0) ? aA0 : (vs == 1) ? aA1 : (vs == 2) ? aA2 : aA3;
        float sB = (vs == 0) ? aB0 : (vs == 1) ? aB1 : (vs == 2) ? aB2 : aB3;
        sA += xpA + biasA;
        sB += xpB + biasB;
        float sigA = 1.f / (1.f + __expf(-sA));
        float sigB = 1.f / (1.f + __expf(-sB));
        // gate exchange: even-vs lanes pull partner's k-gate
        float kgA = dpp_mov<0xB1>(sigA);               // xor1
        float kgB = dpp_mov<0xB1>(sigB);
        float hnA = sigA + hregA * (1.f - sigA - kgA); // valid at vs0, vs2
        float hnB = sigB + hregB * (1.f - sigB - kgB);
        hregA = hnA;
        hregB = hnB;
        float hn1A = dpp_mov<0x4E>(hnA);               // odd-u hn -> vs0
        float hn1B = dpp_mov<0x4E>(hnB);
        if (vs == 0) {
            h2_t pA; pA.x = (_Float16)hnA; pA.y = (_Float16)hn1A;
            h2_t pB; pB.x = (_Float16)hnB; pB.y = (_Float16)hn1B;
            int idx0 = (up0 >> 4) * 20 + (up0 & 15);   // pair B slice = +4 -> +80 words
            hnext[idx0]      = __builtin_bit_cast(uint32_t, pA);
            hnext[idx0 + 80] = __builtin_bit_cast(uint32_t, pB);
            *(float2*)(hsb + (size_t)t * 256)       = make_float2(hnA, hn1A);
            *(float2*)(hsb + (size_t)t * 256 + 128) = make_float2(hnB, hn1B);
        }
        __syncthreads();
    }
}

// ---------------------------------------------------------------------------
// K3: oscillator expansion (memory-bound). (unchanged)
// ---------------------------------------------------------------------------
__global__ __launch_bounds__(256) void osc(const float* __restrict__ hs,
                                           float* __restrict__ out) {
    int tid = blockIdx.x * 256 + threadIdx.x;   // 1,638,400
    const int cstride = 32 * 200 * 256;
    int u = tid & 255;
    int bt = tid >> 8;
    int t = bt % 200, b = bt / 200;
    float phi   = hs[0 * cstride + tid];
    float omega = hs[1 * cstride + tid];
    float r     = hs[2 * cstride + tid];
    float mu    = hs[3 * cstride + tid];
    float* o = out + ((size_t)(b * 2000 + t * 10)) * 256 + u;
#pragma unroll
    for (int s = 0; s < 10; s++) {
        o[(size_t)s * 256] = r * __cosf(phi);
        r = r + (mu - r * r) * r;
        phi = phi + omega;
    }
}

// ---------------------------------------------------------------------------
extern "C" void kernel_launch(void* const* d_in, const int* in_sizes, int n_in,
                              void* d_out, int out_size, void* d_ws, size_t ws_size,
                              hipStream_t stream) {
    const float* x  = (const float*)d_in[0];
    const float* Wx = (const float*)d_in[1];
    const float* bx = (const float*)d_in[2];
    const float* Wh = (const float*)d_in[3];
    const float* bh = (const float*)d_in[4];
    float* out = (float*)d_out;

    char* ws = (char*)d_ws;
    const size_t XP = (size_t)4 * 32 * 200 * 512 * 2;   // 26.2 MB f16
    const size_t HS = (size_t)4 * 32 * 200 * 256 * 4;   // 26.2 MB f32
    const size_t XH = (size_t)6400 * 256 * 2;           // 3.28 MB

    _Float16* xp  = (_Float16*)ws;
    float*    hs  = (float*)(ws + XP);
    // xh/wxt alias the hs region: they are dead before recurrence writes hs.
    _Float16* xh  = (_Float16*)(ws + XP);
    _Float16* wxt = (_Float16*)(ws + XP + XH);
    uint32_t* wp  = (uint32_t*)(ws + XP + HS);

    pack_all<<<9472, 256, 0, stream>>>(x, Wx, Wh, xh, wxt, wp);
    xp_gemm<<<800, 256, 0, stream>>>(xh, wxt, bx, xp);
    recurrence<<<128, 512, 0, stream>>>(xp, bh, wp, hs);
    osc<<<6400, 256, 0, stream>>>(hs, out);
}

// Round 2
// 344.914 us; speedup vs baseline: 1.1052x; 1.1052x over previous
//
#include <hip/hip_runtime.h>
#include <hip/hip_fp16.h>
#include <stdint.h>

#define TS 200

typedef _Float16 h2_t  __attribute__((ext_vector_type(2)));
typedef _Float16 f16x8 __attribute__((ext_vector_type(8)));
typedef float    f32x4 __attribute__((ext_vector_type(4)));

static __device__ __forceinline__ float fdot2f(uint32_t w, uint32_t h, float acc) {
#if __has_builtin(__builtin_amdgcn_fdot2)
    return __builtin_amdgcn_fdot2(__builtin_bit_cast(h2_t, w),
                                  __builtin_bit_cast(h2_t, h), acc, false);
#else
    h2_t a = __builtin_bit_cast(h2_t, w), b = __builtin_bit_cast(h2_t, h);
    acc = fmaf((float)a.x, (float)b.x, acc);
    acc = fmaf((float)a.y, (float)b.y, acc);
    return acc;
#endif
}

template <int CTRL>
static __device__ __forceinline__ float dpp_add(float x) {
    int m = __builtin_amdgcn_update_dpp(0, __builtin_bit_cast(int, x), CTRL, 0xF, 0xF, true);
    return x + __builtin_bit_cast(float, m);
}
template <int CTRL>
static __device__ __forceinline__ float dpp_mov(float x) {
    int m = __builtin_amdgcn_update_dpp(0, __builtin_bit_cast(int, x), CTRL, 0xF, 0xF, true);
    return __builtin_bit_cast(float, m);
}

// ---------------------------------------------------------------------------
// K0: one-time packs (unchanged).
// ---------------------------------------------------------------------------
__global__ __launch_bounds__(256) void pack_all(const float* __restrict__ x,
                                                const float* __restrict__ Wx,
                                                const float* __restrict__ Wh,
                                                _Float16* __restrict__ xh,
                                                _Float16* __restrict__ wxt,
                                                uint32_t* __restrict__ wp) {
    int bid = blockIdx.x, tid = threadIdx.x;
    if (bid < 6400) {
        int row = bid, col = tid;
        int b = row / 200, t = row - b * 200;
        xh[(size_t)row * 256 + col] = (_Float16)x[((size_t)(b * 2000 + t * 10)) * 256 + col];
    } else if (bid < 8448) {
        int n = bid - 6400, k = tid;
        wxt[(size_t)n * 256 + k] = (_Float16)Wx[((size_t)((n >> 8) * 256 + k)) * 256 + (n & 255)];
    } else {
        int idx = (bid - 8448) * 256 + tid;          // [0, 262144)
        int e   = idx & 3;
        int thr = (idx >> 2) & 1023;
        int j   = (idx >> 12) & 15;
        int c   = idx >> 16;
        int a = j >> 2, i = j & 3;
        int uu = a >> 1, g = a & 1;
        int vs = thr & 7, uq = (thr >> 3) & 7, wv = thr >> 6;
        int u = (wv * 8 + uq) * 2 + uu;
        int v = vs * 32 + i * 8 + e * 2;
        const float* base = Wh + ((size_t)((c * 2 + g) * 256 + v)) * 256 + u;
        h2_t p; p.x = (_Float16)base[0]; p.y = (_Float16)base[256];
        wp[idx] = __builtin_bit_cast(uint32_t, p);
    }
}

// ---------------------------------------------------------------------------
// K1: xp = X[6400x256] * W[256x2048] + bias, f16 MFMA 16x16x32. (unchanged)
// ---------------------------------------------------------------------------
__global__ __launch_bounds__(256) void xp_gemm(const _Float16* __restrict__ xh,
                                               const _Float16* __restrict__ wxt,
                                               const float* __restrict__ bxf,
                                               _Float16* __restrict__ xp) {
    __shared__ _Float16 As[128 * 64];
    __shared__ _Float16 Bs[128 * 64];
    const int tid = threadIdx.x;
    const int lane = tid & 63, w = tid >> 6;
    const int m0 = (blockIdx.x >> 4) * 128;
    const int n0 = (blockIdx.x & 15) * 128;
    const int mw = (w & 1) * 64, nw = (w >> 1) * 64;

    f32x4 acc[4][4] = {};

    for (int kb = 0; kb < 4; kb++) {
        const int k0 = kb * 64;
#pragma unroll
        for (int q = 0; q < 4; q++) {
            int ii = w * 4 + q;
            int r = ii * 8 + (lane >> 3);
            int kcol = (lane & 7) * 8;
            const _Float16* ga = xh  + (size_t)(m0 + r) * 256 + k0 + kcol;
            const _Float16* gb = wxt + (size_t)(n0 + r) * 256 + k0 + kcol;
            __builtin_amdgcn_global_load_lds(
                (const __attribute__((address_space(1))) uint32_t*)ga,
                (__attribute__((address_space(3))) uint32_t*)(As + ii * 512), 16, 0, 0);
            __builtin_amdgcn_global_load_lds(
                (const __attribute__((address_space(1))) uint32_t*)gb,
                (__attribute__((address_space(3))) uint32_t*)(Bs + ii * 512), 16, 0, 0);
        }
        __syncthreads();
#pragma unroll
        for (int kc = 0; kc < 2; kc++) {
            f16x8 a[4], b[4];
#pragma unroll
            for (int mt = 0; mt < 4; mt++)
                a[mt] = *(const f16x8*)&As[(mw + mt * 16 + (lane & 15)) * 64 + kc * 32 + (lane >> 4) * 8];
#pragma unroll
            for (int nt = 0; nt < 4; nt++)
                b[nt] = *(const f16x8*)&Bs[(nw + nt * 16 + (lane & 15)) * 64 + kc * 32 + (lane >> 4) * 8];
#pragma unroll
            for (int mt = 0; mt < 4; mt++)
#pragma unroll
                for (int nt = 0; nt < 4; nt++)
                    acc[mt][nt] = __builtin_amdgcn_mfma_f32_16x16x32_f16(a[mt], b[nt], acc[mt][nt], 0, 0, 0);
        }
        __syncthreads();
    }

    const int nl = lane & 15, quad = lane >> 4;
#pragma unroll
    for (int nt = 0; nt < 4; nt++) {
        int n = n0 + nw + nt * 16 + nl;
        float bias = bxf[n];
        int c = n >> 9, gu = n & 511;
#pragma unroll
        for (int mt = 0; mt < 4; mt++)
#pragma unroll
            for (int r = 0; r < 4; r++) {
                int m = m0 + mw + mt * 16 + quad * 4 + r;
                int b = m / 200, t = m - b * 200;
                xp[((size_t)((c * 32 + b) * 200 + t)) * 512 + gu] =
                    (_Float16)(acc[mt][nt][r] + bias);
            }
    }
}

// ---------------------------------------------------------------------------
// K2: 200-step gated recurrence. 128 WGs (c,b) x 512 threads.
// R2 changes (data layout untouched):
//  * __syncthreads() -> s_waitcnt lgkmcnt(0) + raw s_barrier. HIP's
//    __syncthreads drains vmcnt(0) every step, serializing the xp global
//    load + hs store-ack (~2000 cy/step of exposed latency). Only LDS
//    ordering is required for the h exchange; xp/hs need no barrier order.
//  * xp loads batched 8 steps ahead into a register double buffer -> one
//    (pipelined) load-wait per 8 steps instead of a cold load per step.
//  * hs stores stay per-step but are now fire-and-forget.
// ---------------------------------------------------------------------------
#define D4(ACC, W, H)                 \
    ACC = fdot2f(W.x, H.x, ACC);      \
    ACC = fdot2f(W.y, H.y, ACC);      \
    ACC = fdot2f(W.z, H.z, ACC);      \
    ACC = fdot2f(W.w, H.w, ACC);

#define PIN4(W) asm volatile("" : "+v"(W.x), "+v"(W.y), "+v"(W.z), "+v"(W.w))

#define LDS_BARRIER()                                        \
    do {                                                     \
        __builtin_amdgcn_sched_barrier(0);                   \
        asm volatile("s_waitcnt lgkmcnt(0)" ::: "memory");   \
        __builtin_amdgcn_s_barrier();                        \
        __builtin_amdgcn_sched_barrier(0);                   \
    } while (0)

__global__ __attribute__((amdgpu_flat_work_group_size(512, 512),
                          amdgpu_waves_per_eu(2, 2)))
void recurrence(const _Float16* __restrict__ xp,
                const float* __restrict__ bh,
                const uint32_t* __restrict__ Wp,
                float* __restrict__ hs) {
    const int cb  = blockIdx.x;            // c*32+b
    const int c   = cb >> 5;
    const int tid = threadIdx.x;           // 0..511
    const int lane = tid & 63;
    const int vs = lane & 7;
    const int uq = lane >> 3;
    const int wv = tid >> 6;               // 0..7
    const int up0 = wv * 8 + uq;           // 0..63 ; pair B = up0+64
    const int u0 = up0 * 2;                // pair B u = u0+128

    // h2s double buffer: 2 x (8 slices x 20 words) — stride-20 bank partition
    __shared__ __align__(16) uint32_t h2s[2][160];

    // 32 named uint4 weights = 128 half2. Set A = old thread tid, set B = old
    // thread tid+512 (same vs/uq, wv+8 -> upair+64). wp layout unchanged.
    const uint4* wb = (const uint4*)Wp + (size_t)c * 16 * 1024 + tid;
    uint4 wA00 = wb[0 * 1024],        wA01 = wb[1 * 1024],        wA02 = wb[2 * 1024],        wA03 = wb[3 * 1024];
    uint4 wA10 = wb[4 * 1024],        wA11 = wb[5 * 1024],        wA12 = wb[6 * 1024],        wA13 = wb[7 * 1024];
    uint4 wA20 = wb[8 * 1024],        wA21 = wb[9 * 1024],        wA22 = wb[10 * 1024],       wA23 = wb[11 * 1024];
    uint4 wA30 = wb[12 * 1024],       wA31 = wb[13 * 1024],       wA32 = wb[14 * 1024],       wA33 = wb[15 * 1024];
    uint4 wB00 = wb[0 * 1024 + 512],  wB01 = wb[1 * 1024 + 512],  wB02 = wb[2 * 1024 + 512],  wB03 = wb[3 * 1024 + 512];
    uint4 wB10 = wb[4 * 1024 + 512],  wB11 = wb[5 * 1024 + 512],  wB12 = wb[6 * 1024 + 512],  wB13 = wb[7 * 1024 + 512];
    uint4 wB20 = wb[8 * 1024 + 512],  wB21 = wb[9 * 1024 + 512],  wB22 = wb[10 * 1024 + 512], wB23 = wb[11 * 1024 + 512];
    uint4 wB30 = wb[12 * 1024 + 512], wB31 = wb[13 * 1024 + 512], wB32 = wb[14 * 1024 + 512], wB33 = wb[15 * 1024 + 512];
    PIN4(wA00); PIN4(wA01); PIN4(wA02); PIN4(wA03);
    PIN4(wA10); PIN4(wA11); PIN4(wA12); PIN4(wA13);
    PIN4(wA20); PIN4(wA21); PIN4(wA22); PIN4(wA23);
    PIN4(wA30); PIN4(wA31); PIN4(wA32); PIN4(wA33);
    PIN4(wB00); PIN4(wB01); PIN4(wB02); PIN4(wB03);
    PIN4(wB10); PIN4(wB11); PIN4(wB12); PIN4(wB13);
    PIN4(wB20); PIN4(wB21); PIN4(wB22); PIN4(wB23);
    PIN4(wB30); PIN4(wB31); PIN4(wB32); PIN4(wB33);

    // xp / bias for reduce lanes (vs<4): (u = u0 + (vs>>1), g = vs&1); B at +128
    float biasA = 0.f, biasB = 0.f;
    const _Float16* xpb = nullptr;
    if (vs < 4) {
        int g_sel = vs & 1, u_sel = u0 + (vs >> 1);
        biasA = bh[(c * 2 + g_sel) * 256 + u_sel];
        biasB = bh[(c * 2 + g_sel) * 256 + u_sel + 128];
        xpb  = xp + (size_t)cb * 200 * 512 + g_sel * 256 + u_sel;
    }

    float hregA = 0.f, hregB = 0.f;        // valid at vs==0 (u even) / vs==2 (u odd)
    if (tid < 160) { h2s[0][tid] = 0u; }
    __syncthreads();

    float* hsb = hs + (size_t)cb * 200 * 256 + u0;   // B at +128

    // xp register double buffer: 8 steps per block, prefetched one block ahead
    _Float16 curA[8] = {}, curB[8] = {}, nxtA[8] = {}, nxtB[8] = {};
    if (vs < 4) {
#pragma unroll
        for (int s = 0; s < 8; s++) {
            curA[s] = xpb[(size_t)s * 512];
            curB[s] = xpb[(size_t)s * 512 + 128];
        }
    }

    for (int tb = 0; tb < TS; tb += 8) {
        // issue next block's loads early; latency hides under 8 steps of compute
        if (vs < 4 && tb + 8 < TS) {
#pragma unroll
            for (int s = 0; s < 8; s++) {
                nxtA[s] = xpb[(size_t)(tb + 8 + s) * 512];
                nxtB[s] = xpb[(size_t)(tb + 8 + s) * 512 + 128];
            }
        }
#pragma unroll
        for (int s = 0; s < 8; s++) {
            const int t = tb + s;
            const uint32_t* hbuf = h2s[t & 1];
            uint32_t* hnext = h2s[(t + 1) & 1];

            float xpA = 0.f, xpB = 0.f;
            if (vs < 4) {
                xpA = (float)curA[s];
                xpB = (float)curB[s];
            }

            uint4 h0 = *(const uint4*)(hbuf + vs * 20 + 0);
            uint4 h1 = *(const uint4*)(hbuf + vs * 20 + 4);
            uint4 h2 = *(const uint4*)(hbuf + vs * 20 + 8);
            uint4 h3 = *(const uint4*)(hbuf + vs * 20 + 12);

            float aA0 = 0.f, aA1 = 0.f, aA2 = 0.f, aA3 = 0.f;
            float aB0 = 0.f, aB1 = 0.f, aB2 = 0.f, aB3 = 0.f;
            // 8 independent chains, A/B interleaved for ILP
            D4(aA0, wA00, h0) D4(aB0, wB00, h0) D4(aA1, wA10, h0) D4(aB1, wB10, h0)
            D4(aA2, wA20, h0) D4(aB2, wB20, h0) D4(aA3, wA30, h0) D4(aB3, wB30, h0)
            D4(aA0, wA01, h1) D4(aB0, wB01, h1) D4(aA1, wA11, h1) D4(aB1, wB11, h1)
            D4(aA2, wA21, h1) D4(aB2, wB21, h1) D4(aA3, wA31, h1) D4(aB3, wB31, h1)
            D4(aA0, wA02, h2) D4(aB0, wB02, h2) D4(aA1, wA12, h2) D4(aB1, wB12, h2)
            D4(aA2, wA22, h2) D4(aB2, wB22, h2) D4(aA3, wA32, h2) D4(aB3, wB32, h2)
            D4(aA0, wA03, h3) D4(aB0, wB03, h3) D4(aA1, wA13, h3) D4(aB1, wB13, h3)
            D4(aA2, wA23, h3) D4(aB2, wB23, h3) D4(aA3, wA33, h3) D4(aB3, wB33, h3)

            aA0 = dpp_add<0x141>(dpp_add<0x4E>(dpp_add<0xB1>(aA0)));
            aA1 = dpp_add<0x141>(dpp_add<0x4E>(dpp_add<0xB1>(aA1)));
            aA2 = dpp_add<0x141>(dpp_add<0x4E>(dpp_add<0xB1>(aA2)));
            aA3 = dpp_add<0x141>(dpp_add<0x4E>(dpp_add<0xB1>(aA3)));
            aB0 = dpp_add<0x141>(dpp_add<0x4E>(dpp_add<0xB1>(aB0)));
            aB1 = dpp_add<0x141>(dpp_add<0x4E>(dpp_add<0xB1>(aB1)));
            aB2 = dpp_add<0x141>(dpp_add<0x4E>(dpp_add<0xB1>(aB2)));
            aB3 = dpp_add<0x141>(dpp_add<0x4E>(dpp_add<0xB1>(aB3)));

            // lane vs -> acc index: vs0:(u even,j) vs1:(u even,k) vs2:(u odd,j) vs3:(u odd,k)
            float sA = (vs == 0) ? aA0 : (vs == 1) ? aA1 : (vs == 2) ? aA2 : aA3;
            float sB = (vs == 0) ? aB0 : (vs == 1) ? aB1 : (vs == 2) ? aB2 : aB3;
            sA += xpA + biasA;
            sB += xpB + biasB;
            float sigA = 1.f / (1.f + __expf(-sA));
            float sigB = 1.f / (1.f + __expf(-sB));
            // gate exchange: even-vs lanes pull partner's k-gate
            float kgA = dpp_mov<0xB1>(sigA);               // xor1
            float kgB = dpp_mov<0xB1>(sigB);
            float hnA = sigA + hregA * (1.f - sigA - kgA); // valid at vs0, vs2
            float hnB = sigB + hregB * (1.f - sigB - kgB);
            hregA = hnA;
            hregB = hnB;
            float hn1A = dpp_mov<0x4E>(hnA);               // odd-u hn -> vs0
            float hn1B = dpp_mov<0x4E>(hnB);
            if (vs == 0) {
                h2_t pA; pA.x = (_Float16)hnA; pA.y = (_Float16)hn1A;
                h2_t pB; pB.x = (_Float16)hnB; pB.y = (_Float16)hn1B;
                int idx0 = (up0 >> 4) * 20 + (up0 & 15);   // pair B slice = +80 words
                hnext[idx0]      = __builtin_bit_cast(uint32_t, pA);
                hnext[idx0 + 80] = __builtin_bit_cast(uint32_t, pB);
                *(float2*)(hsb + (size_t)t * 256)       = make_float2(hnA, hn1A);
                *(float2*)(hsb + (size_t)t * 256 + 128) = make_float2(hnB, hn1B);
            }
            // LDS-only fence: global loads/stores stay in flight across barrier
            LDS_BARRIER();
        }
        if (vs < 4) {
#pragma unroll
            for (int s = 0; s < 8; s++) { curA[s] = nxtA[s]; curB[s] = nxtB[s]; }
        }
    }
}

// ---------------------------------------------------------------------------
// K3: oscillator expansion (memory-bound). (unchanged)
// ---------------------------------------------------------------------------
__global__ __launch_bounds__(256) void osc(const float* __restrict__ hs,
                                           float* __restrict__ out) {
    int tid = blockIdx.x * 256 + threadIdx.x;   // 1,638,400
    const int cstride = 32 * 200 * 256;
    int u = tid & 255;
    int bt = tid >> 8;
    int t = bt % 200, b = bt / 200;
    float phi   = hs[0 * cstride + tid];
    float omega = hs[1 * cstride + tid];
    float r     = hs[2 * cstride + tid];
    float mu    = hs[3 * cstride + tid];
    float* o = out + ((size_t)(b * 2000 + t * 10)) * 256 + u;
#pragma unroll
    for (int s = 0; s < 10; s++) {
        o[(size_t)s * 256] = r * __cosf(phi);
        r = r + (mu - r * r) * r;
        phi = phi + omega;
    }
}

// ---------------------------------------------------------------------------
extern "C" void kernel_launch(void* const* d_in, const int* in_sizes, int n_in,
                              void* d_out, int out_size, void* d_ws, size_t ws_size,
                              hipStream_t stream) {
    const float* x  = (const float*)d_in[0];
    const float* Wx = (const float*)d_in[1];
    const float* bx = (const float*)d_in[2];
    const float* Wh = (const float*)d_in[3];
    const float* bh = (const float*)d_in[4];
    float* out = (float*)d_out;

    char* ws = (char*)d_ws;
    const size_t XP = (size_t)4 * 32 * 200 * 512 * 2;   // 26.2 MB f16
    const size_t HS = (size_t)4 * 32 * 200 * 256 * 4;   // 26.2 MB f32
    const size_t XH = (size_t)6400 * 256 * 2;           // 3.28 MB

    _Float16* xp  = (_Float16*)ws;
    float*    hs  = (float*)(ws + XP);
    // xh/wxt alias the hs region: they are dead before recurrence writes hs.
    _Float16* xh  = (_Float16*)(ws + XP);
    _Float16* wxt = (_Float16*)(ws + XP + XH);
    uint32_t* wp  = (uint32_t*)(ws + XP + HS);

    pack_all<<<9472, 256, 0, stream>>>(x, Wx, Wh, xh, wxt, wp);
    xp_gemm<<<800, 256, 0, stream>>>(xh, wxt, bx, xp);
    recurrence<<<128, 512, 0, stream>>>(xp, bh, wp, hs);
    osc<<<6400, 256, 0, stream>>>(hs, out);
}